// Round 3
// baseline (31.157 us; speedup 1.0000x reference)
//
#include <hip/hip_runtime.h>
#include <float.h>
#include <math.h>

#define BB 8
#define PP 4096
#define QW 1024     // queries per block (shared by all 16 waves)
#define QPL 16      // queries per lane
#define SEGN 64     // neighbors per wave
#define NBBLK 1024  // neighbors per block (one quarter of the cloud)

// Pass 1: per (dir, cloud, qgroup, seg) block: for each of 1024 queries,
// min over 1024 neighbors of t = |c|^2/2 - a.c; store s = |a|^2/2 + min_t.
// (min is order-preserving under the constant per-query |a|^2/2 shift, so
// cross-seg combining in pass 2 needs only ws.)
__global__ __launch_bounds__(1024) void chamfer_pass1(
    const float* __restrict__ y1, const float* __restrict__ y2,
    float* __restrict__ ws)
{
    __shared__ float4 nb[NBBLK];      // 16 KB: (x, y, z, |c|^2/2)
    __shared__ float pmin[16][QW];    // 64 KB: per-wave partial mins

    const int bid   = blockIdx.x;
    const int seg   = bid & 3;
    const int combo = bid >> 2;       // dir*32 + cloud*4 + qg
    const int qg    = combo & 3;
    const int cloud = (combo >> 2) & 7;
    const int dir   = combo >> 5;

    const float* src = (dir == 0) ? y1 : y2;
    const float* tgt = (dir == 0) ? y2 : y1;
    const float* __restrict__ tgt_base = tgt + ((size_t)cloud * PP + (size_t)seg * NBBLK) * 3;
    const float* __restrict__ src_base = src + ((size_t)cloud * PP + (size_t)qg  * QW)    * 3;

    const int tid  = threadIdx.x;
    const int lane = tid & 63;
    const int w    = tid >> 6;

    // Stage 1024 neighbors into LDS as (x,y,z,h), one per thread.
    {
        const float* g = tgt_base + (size_t)tid * 3;
        const float x = g[0], yv = g[1], z = g[2];
        nb[tid] = make_float4(x, yv, z, 0.5f * (x * x + yv * yv + z * z));
    }

    // Each lane owns 16 query points (pre-negated for the FMA chain).
    float nax[QPL], nay[QPL], naz[QPL], acc[QPL];
    #pragma unroll
    for (int k = 0; k < QPL; ++k) {
        const float* q = src_base + (size_t)(lane + k * 64) * 3;
        nax[k] = -q[0]; nay[k] = -q[1]; naz[k] = -q[2];
        acc[k] = FLT_MAX;
    }
    __syncthreads();

    // Main loop: wave-uniform broadcast ds_read_b128, amortized over 16 queries.
    const int jb = w * SEGN;
    for (int i = 0; i < SEGN; i += 4) {
        const float4 c0 = nb[jb + i + 0];
        const float4 c1 = nb[jb + i + 1];
        const float4 c2 = nb[jb + i + 2];
        const float4 c3 = nb[jb + i + 3];
        #pragma unroll
        for (int k = 0; k < QPL; ++k) {
            float t0 = fmaf(nax[k], c0.x, fmaf(nay[k], c0.y, fmaf(naz[k], c0.z, c0.w)));
            float t1 = fmaf(nax[k], c1.x, fmaf(nay[k], c1.y, fmaf(naz[k], c1.z, c1.w)));
            acc[k] = fminf(fminf(t0, t1), acc[k]);   // v_min3 pattern
            float t2 = fmaf(nax[k], c2.x, fmaf(nay[k], c2.y, fmaf(naz[k], c2.z, c2.w)));
            float t3 = fmaf(nax[k], c3.x, fmaf(nay[k], c3.y, fmaf(naz[k], c3.z, c3.w)));
            acc[k] = fminf(fminf(t2, t3), acc[k]);
        }
    }

    #pragma unroll
    for (int k = 0; k < QPL; ++k)
        pmin[w][lane + k * 64] = acc[k];
    __syncthreads();

    // Combine the 16 waves' partial mins; fold in |a|^2/2; write per-(seg, query).
    {
        float m = pmin[0][tid];
        #pragma unroll
        for (int ww = 1; ww < 16; ++ww)
            m = fminf(m, pmin[ww][tid]);
        const float* qv = src_base + (size_t)tid * 3;  // L1-hot reload
        const float aa2 = 0.5f * (qv[0] * qv[0] + qv[1] * qv[1] + qv[2] * qv[2]);
        ws[(size_t)seg * 65536 + (size_t)combo * QW + tid] = m + aa2;
    }
}

// Pass 2: per query, min over the 4 segs, d = sqrt(2*s_min), block-sum.
__global__ __launch_bounds__(1024) void chamfer_pass2(
    const float* __restrict__ ws, float* __restrict__ partial)
{
    __shared__ float ssum[16];
    const int gq = blockIdx.x * 1024 + threadIdx.x;   // 0..65535
    const float m = fminf(fminf(ws[gq],           ws[65536 + gq]),
                          fminf(ws[131072 + gq],  ws[196608 + gq]));
    float d = sqrtf(fmaxf(0.0f, 2.0f * m));

    #pragma unroll
    for (int off = 32; off > 0; off >>= 1)
        d += __shfl_down(d, off);
    if ((threadIdx.x & 63) == 0)
        ssum[threadIdx.x >> 6] = d;
    __syncthreads();
    if (threadIdx.x < 16) {
        float v = ssum[threadIdx.x];
        #pragma unroll
        for (int off = 8; off > 0; off >>= 1)
            v += __shfl_down(v, off);
        if (threadIdx.x == 0)
            partial[blockIdx.x] = v;
    }
}

// Pass 3: sum 64 block partials, normalize by B*P (gives d1 + d2).
__global__ __launch_bounds__(64) void chamfer_pass3(
    const float* __restrict__ partial, float* __restrict__ out)
{
    float v = partial[threadIdx.x];
    #pragma unroll
    for (int off = 32; off > 0; off >>= 1)
        v += __shfl_down(v, off);
    if (threadIdx.x == 0)
        out[0] = v * (1.0f / (float)(BB * PP));
}

extern "C" void kernel_launch(void* const* d_in, const int* in_sizes, int n_in,
                              void* d_out, int out_size, void* d_ws, size_t ws_size,
                              hipStream_t stream) {
    const float* y1 = (const float*)d_in[0];
    const float* y2 = (const float*)d_in[1];
    float* ws      = (float*)d_ws;            // 262144 floats (1 MB)
    float* partial = ws + 262144;             // +64 floats
    float* out     = (float*)d_out;

    chamfer_pass1<<<256, 1024, 0, stream>>>(y1, y2, ws);
    chamfer_pass2<<<64, 1024, 0, stream>>>(ws, partial);
    chamfer_pass3<<<1, 64, 0, stream>>>(partial, out);
}

// Round 4
// 29.423 us; speedup vs baseline: 1.0590x; 1.0590x over previous
//
#include <hip/hip_runtime.h>
#include <float.h>
#include <math.h>

#define BB 8
#define PP 4096
#define QB 256      // queries per block
#define QPL 4       // queries per lane (4 * 64 = 256)
#define SEGW 256    // neighbors per wave (4096 / 16 waves)

// One block = (dir, cloud, qgroup of 256 queries) vs ALL 4096 neighbors.
// t = |c|^2/2 - a.c is argmin-equivalent to d^2; d^2 = |a|^2 + 2*min_t.
__global__ __launch_bounds__(1024) void chamfer_main(
    const float* __restrict__ y1, const float* __restrict__ y2,
    float* __restrict__ partial)
{
    __shared__ float4 nb[PP];         // 64 KB: (x, y, z, |c|^2/2)
    __shared__ float pmin[16][QB];    // 16 KB: per-wave partial mins
    __shared__ float ssum[4];

    const int bid   = blockIdx.x;
    const int qg    = bid & 15;
    const int cloud = (bid >> 4) & 7;
    const int dir   = bid >> 7;

    const float* src = (dir == 0) ? y1 : y2;
    const float* tgt = (dir == 0) ? y2 : y1;
    const float* __restrict__ tgt_base = tgt + (size_t)cloud * PP * 3;
    const float* __restrict__ src_base = src + ((size_t)cloud * PP + (size_t)qg * QB) * 3;

    const int tid  = threadIdx.x;
    const int lane = tid & 63;
    const int w    = tid >> 6;

    // Stage the whole target cloud into LDS as (x,y,z,h), 4 per thread.
    #pragma unroll
    for (int r = 0; r < 4; ++r) {
        const int idx = tid + r * 1024;
        const float* g = tgt_base + (size_t)idx * 3;
        const float x = g[0], yv = g[1], z = g[2];
        nb[idx] = make_float4(x, yv, z, 0.5f * (x * x + yv * yv + z * z));
    }

    // Each lane owns 4 query points (pre-negated for the FMA chain).
    float nax[QPL], nay[QPL], naz[QPL], acc[QPL];
    #pragma unroll
    for (int k = 0; k < QPL; ++k) {
        const float* q = src_base + (size_t)(lane + k * 64) * 3;
        nax[k] = -q[0]; nay[k] = -q[1]; naz[k] = -q[2];
        acc[k] = FLT_MAX;
    }
    __syncthreads();

    // Main loop: wave-uniform broadcast ds_read_b128, amortized over 4 queries.
    const int jb = w * SEGW;
    for (int i = 0; i < SEGW; i += 4) {
        const float4 c0 = nb[jb + i + 0];
        const float4 c1 = nb[jb + i + 1];
        const float4 c2 = nb[jb + i + 2];
        const float4 c3 = nb[jb + i + 3];
        #pragma unroll
        for (int k = 0; k < QPL; ++k) {
            float t0 = fmaf(nax[k], c0.x, fmaf(nay[k], c0.y, fmaf(naz[k], c0.z, c0.w)));
            float t1 = fmaf(nax[k], c1.x, fmaf(nay[k], c1.y, fmaf(naz[k], c1.z, c1.w)));
            acc[k] = fminf(fminf(t0, t1), acc[k]);   // v_min3 pattern
            float t2 = fmaf(nax[k], c2.x, fmaf(nay[k], c2.y, fmaf(naz[k], c2.z, c2.w)));
            float t3 = fmaf(nax[k], c3.x, fmaf(nay[k], c3.y, fmaf(naz[k], c3.z, c3.w)));
            acc[k] = fminf(fminf(t2, t3), acc[k]);
        }
    }

    #pragma unroll
    for (int k = 0; k < QPL; ++k)
        pmin[w][lane + k * 64] = acc[k];
    __syncthreads();

    // Threads 0..255: combine 16 waves' mins, form distance, block-sum.
    if (tid < QB) {
        float m = pmin[0][tid];
        #pragma unroll
        for (int ww = 1; ww < 16; ++ww)
            m = fminf(m, pmin[ww][tid]);
        const float* qv = src_base + (size_t)tid * 3;  // L1-hot reload
        const float aa = qv[0] * qv[0] + qv[1] * qv[1] + qv[2] * qv[2];
        float d = sqrtf(fmaxf(0.0f, fmaf(2.0f, m, aa)));

        #pragma unroll
        for (int off = 32; off > 0; off >>= 1)
            d += __shfl_down(d, off);
        if ((tid & 63) == 0)
            ssum[tid >> 6] = d;
    }
    __syncthreads();
    if (tid == 0)
        partial[bid] = ssum[0] + ssum[1] + ssum[2] + ssum[3];
}

// Sum 256 block partials, normalize by B*P (gives d1 + d2).
__global__ __launch_bounds__(256) void chamfer_final(
    const float* __restrict__ partial, float* __restrict__ out)
{
    __shared__ float ssum[4];
    const int tid = threadIdx.x;
    float v = partial[tid];
    #pragma unroll
    for (int off = 32; off > 0; off >>= 1)
        v += __shfl_down(v, off);
    if ((tid & 63) == 0)
        ssum[tid >> 6] = v;
    __syncthreads();
    if (tid == 0)
        out[0] = (ssum[0] + ssum[1] + ssum[2] + ssum[3]) * (1.0f / (float)(BB * PP));
}

extern "C" void kernel_launch(void* const* d_in, const int* in_sizes, int n_in,
                              void* d_out, int out_size, void* d_ws, size_t ws_size,
                              hipStream_t stream) {
    const float* y1 = (const float*)d_in[0];
    const float* y2 = (const float*)d_in[1];
    float* partial = (float*)d_ws;    // 256 floats of scratch
    float* out     = (float*)d_out;

    chamfer_main<<<256, 1024, 0, stream>>>(y1, y2, partial);
    chamfer_final<<<1, 256, 0, stream>>>(partial, out);
}